// Round 1
// baseline (172.471 us; speedup 1.0000x reference)
//
#include <hip/hip_runtime.h>
#include <hip/hip_bf16.h>

#define NB 2
#define NH 16
#define SQ 2048
#define DH 64
#define LDK 72   // LDS row stride in shorts: 144B, 16B-aligned, bank-spread

typedef short bf16x8 __attribute__((ext_vector_type(8)));
typedef float f32x4 __attribute__((ext_vector_type(4)));

__device__ __forceinline__ unsigned short f2bf(float f) {
  union { float f; unsigned u; } x; x.f = f;
  unsigned r = x.u + 0x7FFFu + ((x.u >> 16) & 1u);
  return (unsigned short)(r >> 16);
}
__device__ __forceinline__ float bf2f(unsigned short s) {
  union { float f; unsigned u; } x; x.u = ((unsigned)s) << 16;
  return x.f;
}

__global__ __launch_bounds__(256) void attn_causal_fwd(
    const float* __restrict__ q, const float* __restrict__ k,
    const float* __restrict__ v, float* __restrict__ out) {
  __shared__ short khs[64][LDK];   // K tile, bf16 hi
  __shared__ short kls[64][LDK];   // K tile, bf16 lo (residual)
  __shared__ short vts[64][LDK];   // V tile transposed: vts[d][kv]
  __shared__ short pls[4][32][LDK];// per-wave P tile [q_local][kv]

  const int tid  = threadIdx.x;
  const int wave = tid >> 6;
  const int lane = tid & 63;
  const int lo   = lane & 15;
  const int hi   = lane >> 4;

  const int bh    = blockIdx.y;
  const int qb    = (int)gridDim.x - 1 - (int)blockIdx.x; // heavy blocks first
  const int qbase = qb * 128;
  const size_t base = (size_t)bh * SQ * DH;

  // ---- load Q fragments (hi/lo bf16 split), rows = qbase + wave*32 + qt*16 + lo
  bf16x8 qhf[2][2], qlf[2][2];
#pragma unroll
  for (int qt = 0; qt < 2; ++qt) {
#pragma unroll
    for (int ks = 0; ks < 2; ++ks) {
      const float* qp = q + base + (size_t)(qbase + wave * 32 + qt * 16 + lo) * DH + ks * 32 + hi * 8;
#pragma unroll
      for (int j = 0; j < 8; ++j) {
        float f = qp[j];
        unsigned short h = f2bf(f);
        qhf[qt][ks][j] = (short)h;
        qlf[qt][ks][j] = (short)f2bf(f - bf2f(h));
      }
    }
  }

  f32x4 o[2][4];
#pragma unroll
  for (int a = 0; a < 2; ++a)
#pragma unroll
    for (int b = 0; b < 4; ++b)
      o[a][b] = (f32x4){0.f, 0.f, 0.f, 0.f};

  float m_run[2][4], l_run[2][4];
#pragma unroll
  for (int a = 0; a < 2; ++a)
#pragma unroll
    for (int r = 0; r < 4; ++r) { m_run[a][r] = -1e30f; l_run[a][r] = 0.f; }

  const int ntiles = qbase / 64 + 2;  // kv tiles up to and including the diagonal
  for (int t = 0; t < ntiles; ++t) {
    const int kv0 = t * 64;

    // ---- stage K (hi/lo) row-major and V transposed, fp32 -> bf16
#pragma unroll
    for (int i = 0; i < 4; ++i) {
      int idx = i * 256 + tid;        // 0..1023
      int row = idx >> 4;             // kv row 0..63
      int c4  = (idx & 15) << 2;      // d offset 0..60
      float4 kk = *(const float4*)(k + base + (size_t)(kv0 + row) * DH + c4);
      unsigned short h0 = f2bf(kk.x), h1 = f2bf(kk.y), h2 = f2bf(kk.z), h3 = f2bf(kk.w);
      *(short4*)&khs[row][c4] = make_short4((short)h0, (short)h1, (short)h2, (short)h3);
      *(short4*)&kls[row][c4] = make_short4(
          (short)f2bf(kk.x - bf2f(h0)), (short)f2bf(kk.y - bf2f(h1)),
          (short)f2bf(kk.z - bf2f(h2)), (short)f2bf(kk.w - bf2f(h3)));
      float4 vv = *(const float4*)(v + base + (size_t)(kv0 + row) * DH + c4);
      vts[c4 + 0][row] = (short)f2bf(vv.x);
      vts[c4 + 1][row] = (short)f2bf(vv.y);
      vts[c4 + 2][row] = (short)f2bf(vv.z);
      vts[c4 + 3][row] = (short)f2bf(vv.w);
    }
    __syncthreads();

    // ---- S = Q K^T  (hi*hi + hi*lo + lo*hi for near-fp32 accuracy)
    f32x4 sacc[2][4];
#pragma unroll
    for (int qt = 0; qt < 2; ++qt) {
#pragma unroll
      for (int kt = 0; kt < 4; ++kt) {
        f32x4 acc = (f32x4){0.f, 0.f, 0.f, 0.f};
#pragma unroll
        for (int ks = 0; ks < 2; ++ks) {
          bf16x8 bh_ = *(const bf16x8*)&khs[kt * 16 + lo][ks * 32 + hi * 8];
          bf16x8 bl_ = *(const bf16x8*)&kls[kt * 16 + lo][ks * 32 + hi * 8];
          acc = __builtin_amdgcn_mfma_f32_16x16x32_bf16(qhf[qt][ks], bh_, acc, 0, 0, 0);
          acc = __builtin_amdgcn_mfma_f32_16x16x32_bf16(qhf[qt][ks], bl_, acc, 0, 0, 0);
          acc = __builtin_amdgcn_mfma_f32_16x16x32_bf16(qlf[qt][ks], bh_, acc, 0, 0, 0);
        }
        sacc[qt][kt] = acc;
      }
    }

    // ---- causal mask + online softmax + P -> LDS (per-wave region, no barrier)
#pragma unroll
    for (int qt = 0; qt < 2; ++qt) {
#pragma unroll
      for (int r = 0; r < 4; ++r) {
        const int row_g = qbase + wave * 32 + qt * 16 + hi * 4 + r;
        float s0 = (kv0 +  0 + lo <= row_g) ? sacc[qt][0][r] : -1e30f;
        float s1 = (kv0 + 16 + lo <= row_g) ? sacc[qt][1][r] : -1e30f;
        float s2 = (kv0 + 32 + lo <= row_g) ? sacc[qt][2][r] : -1e30f;
        float s3 = (kv0 + 48 + lo <= row_g) ? sacc[qt][3][r] : -1e30f;
        float rmax = fmaxf(fmaxf(s0, s1), fmaxf(s2, s3));
        rmax = fmaxf(rmax, __shfl_xor(rmax, 1));
        rmax = fmaxf(rmax, __shfl_xor(rmax, 2));
        rmax = fmaxf(rmax, __shfl_xor(rmax, 4));
        rmax = fmaxf(rmax, __shfl_xor(rmax, 8));
        float mold = m_run[qt][r];
        float mnew = fmaxf(mold, rmax);
        float scale = __expf(mold - mnew);
        float p0 = __expf(s0 - mnew);
        float p1 = __expf(s1 - mnew);
        float p2 = __expf(s2 - mnew);
        float p3 = __expf(s3 - mnew);
        const int prow = qt * 16 + hi * 4 + r;
        pls[wave][prow][ 0 + lo] = (short)f2bf(p0);
        pls[wave][prow][16 + lo] = (short)f2bf(p1);
        pls[wave][prow][32 + lo] = (short)f2bf(p2);
        pls[wave][prow][48 + lo] = (short)f2bf(p3);
        float ps = (p0 + p1) + (p2 + p3);
        ps += __shfl_xor(ps, 1);
        ps += __shfl_xor(ps, 2);
        ps += __shfl_xor(ps, 4);
        ps += __shfl_xor(ps, 8);
        l_run[qt][r] = l_run[qt][r] * scale + ps;
        m_run[qt][r] = mnew;
#pragma unroll
        for (int dt = 0; dt < 4; ++dt) o[qt][dt][r] *= scale;
      }
    }

    // ---- O += P V   (A = P from per-wave LDS, B = V^T rows)
#pragma unroll
    for (int qt = 0; qt < 2; ++qt) {
#pragma unroll
      for (int dt = 0; dt < 4; ++dt) {
#pragma unroll
        for (int ks = 0; ks < 2; ++ks) {
          bf16x8 a = *(const bf16x8*)&pls[wave][qt * 16 + lo][ks * 32 + hi * 8];
          bf16x8 b = *(const bf16x8*)&vts[dt * 16 + lo][ks * 32 + hi * 8];
          o[qt][dt] = __builtin_amdgcn_mfma_f32_16x16x32_bf16(a, b, o[qt][dt], 0, 0, 0);
        }
      }
    }
    __syncthreads();
  }

  // ---- epilogue: O / l
#pragma unroll
  for (int qt = 0; qt < 2; ++qt) {
#pragma unroll
    for (int r = 0; r < 4; ++r) {
      const int row_g = qbase + wave * 32 + qt * 16 + hi * 4 + r;
      float inv = 1.0f / l_run[qt][r];
#pragma unroll
      for (int dt = 0; dt < 4; ++dt) {
        out[base + (size_t)row_g * DH + dt * 16 + lo] = o[qt][dt][r] * inv;
      }
    }
  }
}

extern "C" void kernel_launch(void* const* d_in, const int* in_sizes, int n_in,
                              void* d_out, int out_size, void* d_ws, size_t ws_size,
                              hipStream_t stream) {
  const float* q = (const float*)d_in[0];
  const float* k = (const float*)d_in[1];
  const float* v = (const float*)d_in[2];
  // d_in[3] is the causal mask; it is tril(ones) by construction -> applied analytically.
  float* out = (float*)d_out;
  dim3 grid(SQ / 128, NB * NH);
  dim3 block(256);
  hipLaunchKernelGGL(attn_causal_fwd, grid, block, 0, stream, q, k, v, out);
}

// Round 2
// 123.710 us; speedup vs baseline: 1.3942x; 1.3942x over previous
//
#include <hip/hip_runtime.h>
#include <hip/hip_bf16.h>

#define NB 2
#define NH 16
#define SQ 2048
#define DH 64

typedef short bf16x8 __attribute__((ext_vector_type(8)));
typedef float f32x16 __attribute__((ext_vector_type(16)));
typedef unsigned u32x2 __attribute__((ext_vector_type(2)));

// 3-bit row swizzle: spreads 16B granules across banks (G4 / T2)
#define SW(r) ((((r) & 7) ^ (((r) >> 3) & 7)))

__device__ __forceinline__ unsigned cvtpk(float a, float b) {
  unsigned r;
  asm volatile("v_cvt_pk_bf16_f32 %0, %1, %2" : "=v"(r) : "v"(a), "v"(b));
  return r;
}
__device__ __forceinline__ float uasf(unsigned u) {
  union { unsigned u; float f; } x; x.u = u; return x.f;
}

union AFrag { unsigned u[4]; bf16x8 v; };

__global__ __launch_bounds__(256) void attn_causal_fwd(
    const float* __restrict__ q, const float* __restrict__ k,
    const float* __restrict__ v, float* __restrict__ out) {
  __shared__ short khs[64][64];  // K tile bf16-hi, XOR-swizzled cols
  __shared__ short kls[64][64];  // K tile bf16-lo residual
  __shared__ short vts[64][64];  // V^T tile: vts[d][kv], swizzled

  const int tid = threadIdx.x;
  const int wave = tid >> 6;
  const int lane = tid & 63;
  const int q31 = lane & 31;
  const int h5 = lane >> 5;

  const int bh = blockIdx.y;
  // pair heavy (qb=15-x) with light (qb=x) on the same CU: ids c and c+256
  // differ only in (y & 16) -> per-CU work is constant 34 tiles.
  const int qb = (blockIdx.y & 16) ? (15 - (int)blockIdx.x) : (int)blockIdx.x;
  const int qbase = qb * 128;
  const size_t base = (size_t)bh * SQ * DH;
  const int qrow_w = qbase + wave * 32;  // wave's 32 q-rows
  const int qg = qrow_w + q31;           // this lane's q row (S layout: q = lane&31)

  // ---- Q fragments, bf16 hi/lo split (B operand of 32x32x16: k = ks*16+h5*8+j)
  bf16x8 qh[4], ql[4];
#pragma unroll
  for (int ks = 0; ks < 4; ++ks) {
    const float* qp = q + base + (size_t)qg * DH + ks * 16 + h5 * 8;
    float4 a = *(const float4*)qp;
    float4 b = *(const float4*)(qp + 4);
    unsigned h0 = cvtpk(a.x, a.y), h1 = cvtpk(a.z, a.w);
    unsigned h2 = cvtpk(b.x, b.y), h3 = cvtpk(b.z, b.w);
    unsigned l0 = cvtpk(a.x - uasf(h0 << 16), a.y - uasf(h0 & 0xffff0000u));
    unsigned l1 = cvtpk(a.z - uasf(h1 << 16), a.w - uasf(h1 & 0xffff0000u));
    unsigned l2 = cvtpk(b.x - uasf(h2 << 16), b.y - uasf(h2 & 0xffff0000u));
    unsigned l3 = cvtpk(b.z - uasf(h3 << 16), b.w - uasf(h3 & 0xffff0000u));
    AFrag fh; fh.u[0] = h0; fh.u[1] = h1; fh.u[2] = h2; fh.u[3] = h3; qh[ks] = fh.v;
    AFrag fl; fl.u[0] = l0; fl.u[1] = l1; fl.u[2] = l2; fl.u[3] = l3; ql[ks] = fl.v;
  }

  f32x16 o0, o1;  // O[q=crow(r,h5)][d = dt*32 + q31]
#pragma unroll
  for (int r = 0; r < 16; ++r) { o0[r] = 0.f; o1[r] = 0.f; }
  float m_run = -1e30f, l_run = 0.f;

  const int ntiles = qbase / 64 + 2;
  float4 kr[4], vr[4];
#pragma unroll
  for (int i = 0; i < 4; ++i) {  // prefetch tile 0
    int idx = i * 256 + tid;
    int row = idx >> 4;
    int c4 = (idx & 15) << 2;
    kr[i] = *(const float4*)(k + base + (size_t)row * DH + c4);
    vr[i] = *(const float4*)(v + base + (size_t)row * DH + c4);
  }

  for (int t = 0; t < ntiles; ++t) {
    const int kv0 = t * 64;
    // ---- stage prefetched regs -> LDS (fp32 -> bf16 hi/lo via cvt_pk)
#pragma unroll
    for (int i = 0; i < 4; ++i) {
      int idx = i * 256 + tid;
      int row = idx >> 4;           // kv row 0..63
      int c4 = (idx & 15) << 2;     // d base
      float4 kk = kr[i];
      unsigned h01 = cvtpk(kk.x, kk.y), h23 = cvtpk(kk.z, kk.w);
      unsigned l01 = cvtpk(kk.x - uasf(h01 << 16), kk.y - uasf(h01 & 0xffff0000u));
      unsigned l23 = cvtpk(kk.z - uasf(h23 << 16), kk.w - uasf(h23 & 0xffff0000u));
      int ci = ((c4 >> 3) ^ SW(row)) * 8 + (c4 & 7);
      *(u32x2*)&khs[row][ci] = (u32x2){h01, h23};
      *(u32x2*)&kls[row][ci] = (u32x2){l01, l23};
      float4 vv = vr[i];
      unsigned v01 = cvtpk(vv.x, vv.y), v23 = cvtpk(vv.z, vv.w);
      int cg = row >> 3, co = row & 7;
      vts[c4 + 0][((cg ^ SW(c4 + 0)) * 8) + co] = (short)(v01 & 0xffffu);
      vts[c4 + 1][((cg ^ SW(c4 + 1)) * 8) + co] = (short)(v01 >> 16);
      vts[c4 + 2][((cg ^ SW(c4 + 2)) * 8) + co] = (short)(v23 & 0xffffu);
      vts[c4 + 3][((cg ^ SW(c4 + 3)) * 8) + co] = (short)(v23 >> 16);
    }
    if (t + 1 < ntiles) {  // issue next tile's loads; in flight during compute
      const int kvn = kv0 + 64;
#pragma unroll
      for (int i = 0; i < 4; ++i) {
        int idx = i * 256 + tid;
        int row = idx >> 4;
        int c4 = (idx & 15) << 2;
        kr[i] = *(const float4*)(k + base + (size_t)(kvn + row) * DH + c4);
        vr[i] = *(const float4*)(v + base + (size_t)(kvn + row) * DH + c4);
      }
    }
    __syncthreads();

    if (kv0 <= qrow_w + 31) {  // wave-uniform activity
      const int nk = (kv0 + 32 <= qrow_w + 31) ? 2 : 1;
      // ---- S^T = K·Q (swapped): D[kv=crow][q=lane&31]; 3-term hi/lo
      f32x16 sa[2];
#pragma unroll
      for (int kt = 0; kt < 2; ++kt) {
        if (kt < nk) {
          f32x16 acc;
#pragma unroll
          for (int r = 0; r < 16; ++r) acc[r] = 0.f;
          const int rr = kt * 32 + q31;
          const int swr = SW(rr);
#pragma unroll
          for (int ks = 0; ks < 4; ++ks) {
            const int gg = ((ks * 2 + h5) ^ swr) * 8;
            bf16x8 ah = *(const bf16x8*)&khs[rr][gg];
            bf16x8 al = *(const bf16x8*)&kls[rr][gg];
            acc = __builtin_amdgcn_mfma_f32_32x32x16_bf16(ah, qh[ks], acc, 0, 0, 0);
            acc = __builtin_amdgcn_mfma_f32_32x32x16_bf16(al, qh[ks], acc, 0, 0, 0);
            acc = __builtin_amdgcn_mfma_f32_32x32x16_bf16(ah, ql[ks], acc, 0, 0, 0);
          }
          if (!(kv0 + kt * 32 + 31 <= qrow_w)) {  // partial tile: causal mask
#pragma unroll
            for (int r = 0; r < 16; ++r) {
              int kvv = kv0 + kt * 32 + (r & 3) + 8 * (r >> 2) + 4 * h5;
              acc[r] = (kvv <= qg) ? acc[r] : -1e30f;
            }
          }
          sa[kt] = acc;
        }
      }
      // ---- online softmax: in-lane reduce + one xor-32 (row split across halves)
      float m16 = -1e30f;
#pragma unroll
      for (int kt = 0; kt < 2; ++kt)
        if (kt < nk)
#pragma unroll
          for (int r = 0; r < 16; ++r) m16 = fmaxf(m16, sa[kt][r]);
      float mm = fmaxf(m16, __shfl_xor(m16, 32));
      if (!__all(mm - m_run <= 8.0f)) {  // T13 defer-rescale
        float mnew = fmaxf(m_run, mm);
        float sc = __expf(m_run - mnew);
        l_run *= sc;
        m_run = mnew;
#pragma unroll
        for (int r = 0; r < 16; ++r) {
          float s_r = __shfl(sc, (r & 3) + 8 * (r >> 2) + 4 * h5);
          o0[r] *= s_r;
          o1[r] *= s_r;
        }
      }
      float rs = 0.f;
      unsigned cpk[2][8];
#pragma unroll
      for (int kt = 0; kt < 2; ++kt) {
        if (kt < nk) {
#pragma unroll
          for (int r = 0; r < 16; ++r) {
            float e = __expf(sa[kt][r] - m_run);
            sa[kt][r] = e;
            rs += e;
          }
#pragma unroll
          for (int i = 0; i < 8; ++i)
            cpk[kt][i] = cvtpk(sa[kt][2 * i], sa[kt][2 * i + 1]);
        }
      }
      rs += __shfl_xor(rs, 32);
      l_run += rs;
      // ---- O += P·V : A-frag built in-register via half-swap (T12-style)
#pragma unroll
      for (int s = 0; s < 4; ++s) {
        if ((s >> 1) < nk) {
          const int kt = s >> 1, s1 = s & 1;
          unsigned P0 = cpk[kt][s1 * 4 + 0], P1 = cpk[kt][s1 * 4 + 1];
          unsigned Q0 = cpk[kt][s1 * 4 + 2], Q1 = cpk[kt][s1 * 4 + 3];
          unsigned X0 = h5 ? Q0 : P0, Z0 = h5 ? P0 : Q0;
          unsigned X1 = h5 ? Q1 : P1, Z1 = h5 ? P1 : Q1;
          unsigned c0 = (unsigned)__shfl_xor((int)Z0, 32);
          unsigned c1 = (unsigned)__shfl_xor((int)Z1, 32);
          AFrag af;
          af.u[0] = h5 ? c0 : X0;  // j=0,1  (kv = 16*s1+8*h5+0,1 from half0)
          af.u[1] = h5 ? c1 : X1;  // j=2,3
          af.u[2] = h5 ? X0 : c0;  // j=4,5  (from half1)
          af.u[3] = h5 ? X1 : c1;  // j=6,7
          const int rr0 = q31;
          const int gg0 = ((s * 2 + h5) ^ SW(rr0)) * 8;
          bf16x8 b0 = *(const bf16x8*)&vts[rr0][gg0];
          o0 = __builtin_amdgcn_mfma_f32_32x32x16_bf16(af.v, b0, o0, 0, 0, 0);
          const int rr1 = 32 + q31;
          const int gg1 = ((s * 2 + h5) ^ SW(rr1)) * 8;
          bf16x8 b1 = *(const bf16x8*)&vts[rr1][gg1];
          o1 = __builtin_amdgcn_mfma_f32_32x32x16_bf16(af.v, b1, o1, 0, 0, 0);
        }
      }
    }
    __syncthreads();
  }

  // ---- epilogue: O / l  (l lives at lane&31 = q; o rows are crow)
  float inv = 1.0f / l_run;
#pragma unroll
  for (int r = 0; r < 16; ++r) {
    int qr = (r & 3) + 8 * (r >> 2) + 4 * h5;
    float ss = __shfl(inv, qr);
    float* op = out + base + (size_t)(qrow_w + qr) * DH + q31;
    op[0] = o0[r] * ss;
    op[32] = o1[r] * ss;
  }
}

extern "C" void kernel_launch(void* const* d_in, const int* in_sizes, int n_in,
                              void* d_out, int out_size, void* d_ws, size_t ws_size,
                              hipStream_t stream) {
  const float* q = (const float*)d_in[0];
  const float* k = (const float*)d_in[1];
  const float* v = (const float*)d_in[2];
  // d_in[3] is the causal mask; it is tril(ones) by construction -> analytic.
  float* out = (float*)d_out;
  dim3 grid(SQ / 128, NB * NH);
  dim3 block(256);
  hipLaunchKernelGGL(attn_causal_fwd, grid, block, 0, stream, q, k, v, out);
}

// Round 3
// 86.213 us; speedup vs baseline: 2.0005x; 1.4349x over previous
//
#include <hip/hip_runtime.h>
#include <hip/hip_bf16.h>

#define NB 2
#define NH 16
#define SQ 2048
#define DH 64
#define LOG2E 1.44269504088896340736f

typedef short bf16x8 __attribute__((ext_vector_type(8)));
typedef float f32x16 __attribute__((ext_vector_type(16)));
typedef unsigned u32x2 __attribute__((ext_vector_type(2)));

// 3-bit granule swizzle: bank-spreads 16B granules (G4 / T2)
#define SW(r) ((((r) & 7) ^ (((r) >> 3) & 7)))

__device__ __forceinline__ unsigned cvtpk(float a, float b) {
  unsigned r;
  asm("v_cvt_pk_bf16_f32 %0, %1, %2" : "=v"(r) : "v"(a), "v"(b));
  return r;
}
__device__ __forceinline__ float uasf(unsigned u) {
  union { unsigned u; float f; } x; x.u = u; return x.f;
}
__device__ __forceinline__ float exp2asm(float x) {  // 2^x
  float r;
  asm("v_exp_f32 %0, %1" : "=v"(r) : "v"(x));
  return r;
}
__device__ __forceinline__ void gll16(const void* g, void* l) {
  __builtin_amdgcn_global_load_lds(
      (const __attribute__((address_space(1))) void*)g,
      (__attribute__((address_space(3))) void*)l, 16, 0, 0);
}

union AFrag { unsigned u[4]; bf16x8 v; };

// ---- pre-pass: K -> bf16 hi/lo (same layout), V -> V^T bf16 [bh][d][S]
__global__ __launch_bounds__(256) void prep_kv(
    const float* __restrict__ k, const float* __restrict__ v,
    short* __restrict__ kh, short* __restrict__ kl, short* __restrict__ vt) {
  __shared__ short vls[64][72];
  const int tid = threadIdx.x;
  const int bh = blockIdx.y;
  const int s0 = blockIdx.x * 64;
  const size_t kbase = ((size_t)bh * SQ + s0) * DH;
#pragma unroll
  for (int i = 0; i < 4; ++i) {
    int idx = i * 256 + tid;
    int row = idx >> 4;
    int c4 = (idx & 15) << 2;
    float4 kk = *(const float4*)(k + kbase + row * DH + c4);
    unsigned h01 = cvtpk(kk.x, kk.y), h23 = cvtpk(kk.z, kk.w);
    unsigned l01 = cvtpk(kk.x - uasf(h01 << 16), kk.y - uasf(h01 & 0xffff0000u));
    unsigned l23 = cvtpk(kk.z - uasf(h23 << 16), kk.w - uasf(h23 & 0xffff0000u));
    *(u32x2*)(kh + kbase + row * DH + c4) = (u32x2){h01, h23};
    *(u32x2*)(kl + kbase + row * DH + c4) = (u32x2){l01, l23};
    float4 vv = *(const float4*)(v + kbase + row * DH + c4);
    unsigned v01 = cvtpk(vv.x, vv.y), v23 = cvtpk(vv.z, vv.w);
    vls[c4 + 0][row] = (short)(v01 & 0xffffu);
    vls[c4 + 1][row] = (short)(v01 >> 16);
    vls[c4 + 2][row] = (short)(v23 & 0xffffu);
    vls[c4 + 3][row] = (short)(v23 >> 16);
  }
  __syncthreads();
#pragma unroll
  for (int i = 0; i < 2; ++i) {
    int idx = i * 256 + tid;
    int d = idx >> 3;
    int ch = (idx & 7) * 8;
    union { short s[8]; bf16x8 v; } t;
#pragma unroll
    for (int j = 0; j < 8; ++j) t.s[j] = vls[d][ch + j];
    *(bf16x8*)(vt + ((size_t)bh * DH + d) * SQ + s0 + ch) = t.v;
  }
}

__global__ __launch_bounds__(256) void attn_causal_fwd(
    const float* __restrict__ q, const short* __restrict__ kh,
    const short* __restrict__ kl, const short* __restrict__ vt,
    float* __restrict__ out) {
  __shared__ short lds[2][3][64][64];  // [dbuf][kh,kl,vt][row][col], 48 KB

  const int tid = threadIdx.x;
  const int wave = tid >> 6;
  const int lane = tid & 63;
  const int q31 = lane & 31;
  const int h5 = lane >> 5;

  // XCD-aware remap: 4 heads per XCD (K/V bf16 3MB fits L2), heavy qb first
  const int lid = (int)blockIdx.y * (int)gridDim.x + (int)blockIdx.x;
  const int bh = (lid & 7) + 8 * ((lid >> 3) & 3);
  const int qb = 15 - (lid >> 5);
  const int qbase = qb * 128;
  const size_t base = (size_t)bh * SQ * DH;
  const int qrow_w = qbase + wave * 32;
  const int qg = qrow_w + q31;

  // ---- staging addresses (pre-swizzled global sources, linear LDS dests)
  const int l8 = lane >> 3, s8 = lane & 7;
  const char* khB = (const char*)(kh + base);
  const char* klB = (const char*)(kl + base);
  const char* vtB = (const char*)(vt + (size_t)bh * DH * SQ);
  int kOffA[2], vOffA[2];
#pragma unroll
  for (int j = 0; j < 2; ++j) {
    int cj = wave * 2 + j;
    int r = cj * 8 + l8;                 // K: kv row / vt: d row
    int sw = (s8 ^ l8 ^ cj) * 16;        // granule ^ SW(r), bytes
    kOffA[j] = r * 128 + sw;
    vOffA[j] = r * 4096 + sw;
  }
#define STAGE(tt, nb)                                                   \
  do {                                                                  \
    size_t kt_ = (size_t)(tt)*8192;                                     \
    size_t vt_ = (size_t)(tt)*128;                                      \
    _Pragma("unroll") for (int j = 0; j < 2; ++j) {                     \
      int cj = wave * 2 + j;                                            \
      gll16(khB + kt_ + kOffA[j], &lds[nb][0][cj * 8][0]);              \
      gll16(klB + kt_ + kOffA[j], &lds[nb][1][cj * 8][0]);              \
      gll16(vtB + vt_ + vOffA[j], &lds[nb][2][cj * 8][0]);              \
    }                                                                   \
  } while (0)

  const int ntiles = qbase / 64 + 2;
  STAGE(0, 0);

  // ---- Q fragments scaled by log2e, bf16 hi/lo split
  bf16x8 qh[4], ql[4];
#pragma unroll
  for (int ks = 0; ks < 4; ++ks) {
    const float* qp = q + base + (size_t)qg * DH + ks * 16 + h5 * 8;
    float4 a = *(const float4*)qp;
    float4 b = *(const float4*)(qp + 4);
    a.x *= LOG2E; a.y *= LOG2E; a.z *= LOG2E; a.w *= LOG2E;
    b.x *= LOG2E; b.y *= LOG2E; b.z *= LOG2E; b.w *= LOG2E;
    unsigned h0 = cvtpk(a.x, a.y), h1 = cvtpk(a.z, a.w);
    unsigned h2 = cvtpk(b.x, b.y), h3 = cvtpk(b.z, b.w);
    unsigned l0 = cvtpk(a.x - uasf(h0 << 16), a.y - uasf(h0 & 0xffff0000u));
    unsigned l1 = cvtpk(a.z - uasf(h1 << 16), a.w - uasf(h1 & 0xffff0000u));
    unsigned l2 = cvtpk(b.x - uasf(h2 << 16), b.y - uasf(h2 & 0xffff0000u));
    unsigned l3 = cvtpk(b.z - uasf(h3 << 16), b.w - uasf(h3 & 0xffff0000u));
    AFrag fh; fh.u[0] = h0; fh.u[1] = h1; fh.u[2] = h2; fh.u[3] = h3; qh[ks] = fh.v;
    AFrag fl; fl.u[0] = l0; fl.u[1] = l1; fl.u[2] = l2; fl.u[3] = l3; ql[ks] = fl.v;
  }

  f32x16 o0, o1;
#pragma unroll
  for (int r = 0; r < 16; ++r) { o0[r] = 0.f; o1[r] = 0.f; }
  float m_run = -1e30f, l_run = 0.f;

  __syncthreads();  // tile 0 staged

  for (int t = 0; t < ntiles; ++t) {
    const int kv0 = t * 64;
    if (t + 1 < ntiles) STAGE(t + 1, (t + 1) & 1);  // in flight across compute

    const short (*khs)[64] = (const short(*)[64])lds[t & 1][0];
    const short (*kls)[64] = (const short(*)[64])lds[t & 1][1];
    const short (*vts)[64] = (const short(*)[64])lds[t & 1][2];

    if (kv0 <= qrow_w + 31) {
      const int nk = (kv0 + 32 <= qrow_w + 31) ? 2 : 1;
      // ---- S^T = K·Q (swapped operands): lane-local P rows; 3-term hi/lo
      f32x16 sa[2];
#pragma unroll
      for (int kt = 0; kt < 2; ++kt) {
        if (kt < nk) {
          f32x16 acc;
#pragma unroll
          for (int r = 0; r < 16; ++r) acc[r] = 0.f;
          const int rr = kt * 32 + q31;
          const int swr = SW(rr);
#pragma unroll
          for (int ks = 0; ks < 4; ++ks) {
            const int gg = ((ks * 2 + h5) ^ swr) * 8;
            bf16x8 ah = *(const bf16x8*)&khs[rr][gg];
            bf16x8 al = *(const bf16x8*)&kls[rr][gg];
            acc = __builtin_amdgcn_mfma_f32_32x32x16_bf16(ah, qh[ks], acc, 0, 0, 0);
            acc = __builtin_amdgcn_mfma_f32_32x32x16_bf16(al, qh[ks], acc, 0, 0, 0);
            acc = __builtin_amdgcn_mfma_f32_32x32x16_bf16(ah, ql[ks], acc, 0, 0, 0);
          }
          if (!(kv0 + kt * 32 + 31 <= qrow_w)) {  // diagonal tile: causal mask
#pragma unroll
            for (int r = 0; r < 16; ++r) {
              int kvv = kv0 + kt * 32 + (r & 3) + 8 * (r >> 2) + 4 * h5;
              acc[r] = (kvv <= qg) ? acc[r] : -1e30f;
            }
          }
          sa[kt] = acc;
        }
      }
      // ---- online softmax (log2 domain), defer-rescale THR=8
      float m16 = -1e30f;
#pragma unroll
      for (int kt = 0; kt < 2; ++kt)
        if (kt < nk)
#pragma unroll
          for (int r = 0; r < 16; ++r) m16 = fmaxf(m16, sa[kt][r]);
      float mm = fmaxf(m16, __shfl_xor(m16, 32));
      if (!__all(mm - m_run <= 8.0f)) {
        float mnew = fmaxf(m_run, mm);
        float sc = exp2asm(m_run - mnew);
        l_run *= sc;
        m_run = mnew;
#pragma unroll
        for (int r = 0; r < 16; ++r) {
          float s_r = __shfl(sc, (r & 3) + 8 * (r >> 2) + 4 * h5);
          o0[r] *= s_r;
          o1[r] *= s_r;
        }
      }
      float rs = 0.f;
      unsigned cpk[2][8];
#pragma unroll
      for (int kt = 0; kt < 2; ++kt) {
        if (kt < nk) {
#pragma unroll
          for (int r = 0; r < 16; ++r) {
            float e = exp2asm(sa[kt][r] - m_run);
            sa[kt][r] = e;
            rs += e;
          }
#pragma unroll
          for (int i = 0; i < 8; ++i)
            cpk[kt][i] = cvtpk(sa[kt][2 * i], sa[kt][2 * i + 1]);
        }
      }
      rs += __shfl_xor(rs, 32);
      l_run += rs;
      // ---- O += P·V : A-frag built in-register via half-swap (T12)
#pragma unroll
      for (int s = 0; s < 4; ++s) {
        if ((s >> 1) < nk) {
          const int kt = s >> 1, s1 = s & 1;
          unsigned P0 = cpk[kt][s1 * 4 + 0], P1 = cpk[kt][s1 * 4 + 1];
          unsigned Q0 = cpk[kt][s1 * 4 + 2], Q1 = cpk[kt][s1 * 4 + 3];
          unsigned X0 = h5 ? Q0 : P0, Z0 = h5 ? P0 : Q0;
          unsigned X1 = h5 ? Q1 : P1, Z1 = h5 ? P1 : Q1;
          unsigned c0 = (unsigned)__shfl_xor((int)Z0, 32);
          unsigned c1 = (unsigned)__shfl_xor((int)Z1, 32);
          AFrag af;
          af.u[0] = h5 ? c0 : X0;
          af.u[1] = h5 ? c1 : X1;
          af.u[2] = h5 ? X0 : c0;
          af.u[3] = h5 ? X1 : c1;
          const int rr0 = q31;
          const int gg0 = ((s * 2 + h5) ^ SW(rr0)) * 8;
          bf16x8 b0 = *(const bf16x8*)&vts[rr0][gg0];
          o0 = __builtin_amdgcn_mfma_f32_32x32x16_bf16(af.v, b0, o0, 0, 0, 0);
          const int rr1 = 32 + q31;
          const int gg1 = ((s * 2 + h5) ^ SW(rr1)) * 8;
          bf16x8 b1 = *(const bf16x8*)&vts[rr1][gg1];
          o1 = __builtin_amdgcn_mfma_f32_32x32x16_bf16(af.v, b1, o1, 0, 0, 0);
        }
      }
    }
    __syncthreads();  // staging of t+1 done (covered by compute), LDS reuse safe
  }

  // ---- epilogue
  float inv = 1.0f / l_run;
#pragma unroll
  for (int r = 0; r < 16; ++r) {
    int qr = (r & 3) + 8 * (r >> 2) + 4 * h5;
    float ss = __shfl(inv, qr);
    float* op = out + base + (size_t)(qrow_w + qr) * DH + q31;
    op[0] = o0[r] * ss;
    op[32] = o1[r] * ss;
  }
}

extern "C" void kernel_launch(void* const* d_in, const int* in_sizes, int n_in,
                              void* d_out, int out_size, void* d_ws, size_t ws_size,
                              hipStream_t stream) {
  const float* q = (const float*)d_in[0];
  const float* k = (const float*)d_in[1];
  const float* v = (const float*)d_in[2];
  // d_in[3] (mask) is tril(ones) by construction -> applied analytically.
  float* out = (float*)d_out;
  const size_t elems = (size_t)NB * NH * SQ * DH;  // 4,194,304
  short* khs = (short*)d_ws;
  short* kls = khs + elems;
  short* vts = kls + elems;

  hipLaunchKernelGGL(prep_kv, dim3(SQ / 64, NB * NH), dim3(256), 0, stream,
                     k, v, khs, kls, vts);
  hipLaunchKernelGGL(attn_causal_fwd, dim3(16, NB * NH), dim3(256), 0, stream,
                     q, khs, kls, vts, out);
}